// Round 1
// baseline (346.401 us; speedup 1.0000x reference)
//
#include <hip/hip_runtime.h>
#include <hip/hip_bf16.h>
#include <math.h>

typedef __bf16 bf16;
typedef __bf16 bf16x8 __attribute__((ext_vector_type(8)));
typedef __bf16 bf16x4 __attribute__((ext_vector_type(4)));
typedef float f32x4 __attribute__((ext_vector_type(4)));

#define EPSc 1.1920929e-07f

static __device__ __forceinline__ void glds16(const void* g, void* l) {
  __builtin_amdgcn_global_load_lds((const __attribute__((address_space(1))) void*)g,
                                   (__attribute__((address_space(3))) void*)l, 16, 0, 0);
}

// ---------------- combine weights: out = sum_k alpha[lidx][k]*base[k] (bf16) ----------
__global__ __launch_bounds__(256) void combine_w(const float* __restrict__ base,
                                                 const float* __restrict__ alpha,
                                                 const int* __restrict__ lidx,
                                                 bf16* __restrict__ out, int n) {
  int li = lidx[0];
  float a0 = alpha[li*4+0], a1 = alpha[li*4+1], a2 = alpha[li*4+2], a3 = alpha[li*4+3];
  size_t i = (size_t)blockIdx.x * blockDim.x + threadIdx.x;
  const float4* b0 = (const float4*)base;
  const float4* b1 = (const float4*)(base + (size_t)n);
  const float4* b2 = (const float4*)(base + 2*(size_t)n);
  const float4* b3 = (const float4*)(base + 3*(size_t)n);
  float4 v0 = b0[i], v1 = b1[i], v2 = b2[i], v3 = b3[i];
  bf16x4 o;
  o[0] = (bf16)(a0*v0.x + a1*v1.x + a2*v2.x + a3*v3.x);
  o[1] = (bf16)(a0*v0.y + a1*v1.y + a2*v2.y + a3*v3.y);
  o[2] = (bf16)(a0*v0.z + a1*v1.z + a2*v2.z + a3*v3.z);
  o[3] = (bf16)(a0*v0.w + a1*v1.w + a2*v2.w + a3*v3.w);
  *(bf16x4*)&out[i*4] = o;
}

// ---------------- rmsnorm: out = x*rsqrt(mean(x^2)+eps)*w*gamma + beta (bf16) --------
__global__ __launch_bounds__(256) void rmsnorm_k(const float* __restrict__ x,
                                                 const float* __restrict__ w,
                                                 const float* __restrict__ gamma,
                                                 const float* __restrict__ beta,
                                                 bf16* __restrict__ out) {
  int row = blockIdx.x, t = threadIdx.x;
  const float4* xr = (const float4*)(x + (size_t)row*1024);
  float4 v = xr[t];
  float ss = v.x*v.x + v.y*v.y + v.z*v.z + v.w*v.w;
  #pragma unroll
  for (int off = 32; off > 0; off >>= 1) ss += __shfl_down(ss, off, 64);
  __shared__ float red[4];
  if ((t & 63) == 0) red[t >> 6] = ss;
  __syncthreads();
  float tot = red[0] + red[1] + red[2] + red[3];
  float r = rsqrtf(tot * (1.0f/1024.0f) + EPSc);
  float4 wv = ((const float4*)w)[t];
  float4 gv = ((const float4*)gamma)[t];
  float4 bv = ((const float4*)beta)[t];
  bf16x4 o;
  o[0] = (bf16)(v.x*r*wv.x*gv.x + bv.x);
  o[1] = (bf16)(v.y*r*wv.y*gv.y + bv.y);
  o[2] = (bf16)(v.z*r*wv.z*gv.z + bv.z);
  o[3] = (bf16)(v.w*r*wv.w*gv.w + bv.w);
  *(bf16x4*)&out[(size_t)row*1024 + t*4] = o;
}

// ---------------- GEMM: C[M,N] = A[M,K] * B[N,K]^T, bf16 in, fp32 acc ----------------
// EP: 0 = store bf16; 1 = fp32 + auxf residual; 3 = silu(auxb)*acc -> bf16;
//     4 = out = x + (x_attn + acc - x)*iter_scale (fp32)
template<int EP>
__global__ __launch_bounds__(256)
void gemm_bt(const bf16* __restrict__ A, const bf16* __restrict__ Bw,
             int M, int N, int K,
             float* __restrict__ outf, bf16* __restrict__ outb,
             const float* __restrict__ auxf, const float* __restrict__ auxf2,
             const bf16* __restrict__ auxb, const float* __restrict__ iscale) {
  __shared__ __align__(16) bf16 As[128*64];
  __shared__ __align__(16) bf16 Bs[128*64];
  const int tid = threadIdx.x, wave = tid >> 6, lane = tid & 63;
  const int lr = lane & 15, lg = lane >> 4;
  const int wr = wave >> 1, wc = wave & 1;
  const int tn0 = blockIdx.x * 128, tm0 = blockIdx.y * 128;
  f32x4 acc[4][4] = {};
  const int rs = lane >> 3, cs = (lane & 7) * 8;

  for (int k0 = 0; k0 < K; k0 += 64) {
    #pragma unroll
    for (int j = 0; j < 4; ++j) {
      int chunk = wave*4 + j;
      int r = chunk*8 + rs;
      glds16(A  + (size_t)(tm0 + r)*K + k0 + cs, &As[chunk*512 + lane*8]);
      glds16(Bw + (size_t)(tn0 + r)*K + k0 + cs, &Bs[chunk*512 + lane*8]);
    }
    __syncthreads();
    #pragma unroll
    for (int kk = 0; kk < 2; ++kk) {
      bf16x8 av[4], bv[4];
      #pragma unroll
      for (int m = 0; m < 4; ++m) av[m] = *(const bf16x8*)&As[(wr*64 + m*16 + lr)*64 + kk*32 + lg*8];
      #pragma unroll
      for (int n = 0; n < 4; ++n) bv[n] = *(const bf16x8*)&Bs[(wc*64 + n*16 + lr)*64 + kk*32 + lg*8];
      #pragma unroll
      for (int m = 0; m < 4; ++m)
        #pragma unroll
        for (int n = 0; n < 4; ++n)
          acc[m][n] = __builtin_amdgcn_mfma_f32_16x16x32_bf16(av[m], bv[n], acc[m][n], 0, 0, 0);
    }
    __syncthreads();
  }

  float its = 0.f;
  if constexpr (EP == 4) its = iscale[0];
  #pragma unroll
  for (int m = 0; m < 4; ++m)
    #pragma unroll
    for (int n = 0; n < 4; ++n)
      #pragma unroll
      for (int i = 0; i < 4; ++i) {
        int row = tm0 + wr*64 + m*16 + lg*4 + i;
        int col = tn0 + wc*64 + n*16 + lr;
        size_t idx = (size_t)row * N + col;
        float v = acc[m][n][i];
        if constexpr (EP == 0) outb[idx] = (bf16)v;
        else if constexpr (EP == 1) outf[idx] = auxf[idx] + v;
        else if constexpr (EP == 3) {
          float g = (float)auxb[idx];
          float s = g / (1.f + __expf(-g));
          outb[idx] = (bf16)(s * v);
        } else if constexpr (EP == 4) {
          float xv = auxf[idx], xa = auxf2[idx];
          outf[idx] = xv + (xa + v - xv) * its;
        }
      }
}

// ---------------- flash attention, causal, H=16 T=2048 HD=64 -------------------------
// qkv: [T][3072] bf16 (q|k|v per head blocks of 64). out: [T][1024] bf16
__global__ __launch_bounds__(256)
void attn_k(const bf16* __restrict__ qkv, bf16* __restrict__ out) {
  const int h = blockIdx.x, qb = blockIdx.y;
  const int tid = threadIdx.x, wave = tid >> 6, lane = tid & 63;
  const int lr = lane & 15, lg = lane >> 4;
  const int q0 = qb * 64;
  __shared__ __align__(16) bf16 Ks[64*72];
  __shared__ __align__(16) bf16 Vt[64*72];
  __shared__ __align__(16) bf16 Ps[4][16*72];

  bf16x8 qf[2];
  {
    const bf16* qrow = qkv + (size_t)(q0 + wave*16 + lr)*3072 + h*64;
    qf[0] = *(const bf16x8*)(qrow + lg*8);
    qf[1] = *(const bf16x8*)(qrow + 32 + lg*8);
  }
  f32x4 o[4] = {};
  float mrow[4], lrow[4];
  #pragma unroll
  for (int i = 0; i < 4; ++i) { mrow[i] = -__builtin_inff(); lrow[i] = 0.f; }

  for (int t = 0; t <= qb; ++t) {
    const int kv0 = t * 64;
    __syncthreads();
    #pragma unroll
    for (int j = 0; j < 2; ++j) {
      int idx = tid + j*256;
      int r = idx >> 3, c = (idx & 7) << 3;
      bf16x8 k8 = *(const bf16x8*)(qkv + (size_t)(kv0 + r)*3072 + 1024 + h*64 + c);
      *(bf16x8*)&Ks[r*72 + c] = k8;
      bf16x8 v8 = *(const bf16x8*)(qkv + (size_t)(kv0 + r)*3072 + 2048 + h*64 + c);
      #pragma unroll
      for (int e = 0; e < 8; ++e) Vt[(c + e)*72 + r] = v8[e];
    }
    __syncthreads();

    f32x4 s[4] = {};
    #pragma unroll
    for (int n = 0; n < 4; ++n) {
      bf16x8 k0f = *(const bf16x8*)&Ks[(n*16 + lr)*72 + lg*8];
      s[n] = __builtin_amdgcn_mfma_f32_16x16x32_bf16(qf[0], k0f, s[n], 0, 0, 0);
      bf16x8 k1f = *(const bf16x8*)&Ks[(n*16 + lr)*72 + 32 + lg*8];
      s[n] = __builtin_amdgcn_mfma_f32_16x16x32_bf16(qf[1], k1f, s[n], 0, 0, 0);
    }
    const int qbase = q0 + wave*16 + lg*4;
    #pragma unroll
    for (int n = 0; n < 4; ++n)
      #pragma unroll
      for (int i = 0; i < 4; ++i) {
        float sv = s[n][i] * 0.125f;
        s[n][i] = (kv0 + n*16 + lr <= qbase + i) ? sv : -__builtin_inff();
      }
    float mnew[4], fac[4], rsum[4];
    #pragma unroll
    for (int i = 0; i < 4; ++i) mnew[i] = fmaxf(fmaxf(s[0][i], s[1][i]), fmaxf(s[2][i], s[3][i]));
    #pragma unroll
    for (int i = 0; i < 4; ++i)
      #pragma unroll
      for (int off = 1; off < 16; off <<= 1) mnew[i] = fmaxf(mnew[i], __shfl_xor(mnew[i], off, 64));
    #pragma unroll
    for (int i = 0; i < 4; ++i) {
      float mt = fmaxf(mrow[i], mnew[i]);
      fac[i] = __expf(mrow[i] - mt);
      mrow[i] = mt;
    }
    #pragma unroll
    for (int n = 0; n < 4; ++n)
      #pragma unroll
      for (int i = 0; i < 4; ++i) s[n][i] = __expf(s[n][i] - mrow[i]);
    #pragma unroll
    for (int i = 0; i < 4; ++i) rsum[i] = s[0][i] + s[1][i] + s[2][i] + s[3][i];
    #pragma unroll
    for (int i = 0; i < 4; ++i)
      #pragma unroll
      for (int off = 1; off < 16; off <<= 1) rsum[i] += __shfl_xor(rsum[i], off, 64);
    #pragma unroll
    for (int i = 0; i < 4; ++i) lrow[i] = lrow[i]*fac[i] + rsum[i];
    #pragma unroll
    for (int nd = 0; nd < 4; ++nd)
      #pragma unroll
      for (int i = 0; i < 4; ++i) o[nd][i] *= fac[i];
    #pragma unroll
    for (int n = 0; n < 4; ++n)
      #pragma unroll
      for (int i = 0; i < 4; ++i) Ps[wave][(lg*4 + i)*72 + n*16 + lr] = (bf16)s[n][i];
    asm volatile("s_waitcnt lgkmcnt(0)" ::: "memory");
    #pragma unroll
    for (int kk = 0; kk < 2; ++kk) {
      bf16x8 pf = *(const bf16x8*)&Ps[wave][lr*72 + kk*32 + lg*8];
      #pragma unroll
      for (int nd = 0; nd < 4; ++nd) {
        bf16x8 vf = *(const bf16x8*)&Vt[(nd*16 + lr)*72 + kk*32 + lg*8];
        o[nd] = __builtin_amdgcn_mfma_f32_16x16x32_bf16(pf, vf, o[nd], 0, 0, 0);
      }
    }
  }
  #pragma unroll
  for (int i = 0; i < 4; ++i) {
    float inv = 1.f / lrow[i];
    #pragma unroll
    for (int nd = 0; nd < 4; ++nd)
      out[(size_t)(q0 + wave*16 + lg*4 + i)*1024 + h*64 + nd*16 + lr] = (bf16)(o[nd][i]*inv);
  }
}

extern "C" void kernel_launch(void* const* d_in, const int* in_sizes, int n_in,
                              void* d_out, int out_size, void* d_ws, size_t ws_size,
                              hipStream_t stream) {
  const float* x        = (const float*)d_in[0];
  const float* gamma    = (const float*)d_in[1];
  const float* beta     = (const float*)d_in[2];
  const float* iscale   = (const float*)d_in[3];
  const float* qkv_b    = (const float*)d_in[4];
  const float* o_b      = (const float*)d_in[5];
  const float* gate_b   = (const float*)d_in[6];
  const float* up_b     = (const float*)d_in[7];
  const float* down_b   = (const float*)d_in[8];
  const float* a_qkv    = (const float*)d_in[9];
  const float* a_o      = (const float*)d_in[10];
  const float* a_gate   = (const float*)d_in[11];
  const float* a_up     = (const float*)d_in[12];
  const float* a_down   = (const float*)d_in[13];
  const float* n1w      = (const float*)d_in[14];
  const float* n2w      = (const float*)d_in[15];
  const int*   lidx     = (const int*)d_in[16];

  char* p = (char*)d_ws;
  auto alloc = [&](size_t bytes) { char* r = p; p += (bytes + 255) & ~(size_t)255; return r; };
  bf16*  Wqkv = (bf16*)alloc((size_t)3072*1024*2);
  bf16*  Wo   = (bf16*)alloc((size_t)1024*1024*2);
  bf16*  Wg   = (bf16*)alloc((size_t)4096*1024*2);
  bf16*  Wu   = (bf16*)alloc((size_t)4096*1024*2);
  bf16*  Wd   = (bf16*)alloc((size_t)1024*4096*2);
  bf16*  hbuf = (bf16*)alloc((size_t)2048*1024*2);
  bf16*  qkvb = (bf16*)alloc((size_t)2048*3072*2);
  bf16*  attn = (bf16*)alloc((size_t)2048*1024*2);
  float* xat  = (float*)alloc((size_t)2048*1024*4);
  bf16*  h2   = (bf16*)alloc((size_t)2048*1024*2);
  bf16*  gate = (bf16*)alloc((size_t)2048*4096*2);
  bf16*  act  = (bf16*)alloc((size_t)2048*4096*2);
  float* out  = (float*)d_out;

  combine_w<<<3072*1024/1024, 256, 0, stream>>>(qkv_b,  a_qkv,  lidx, Wqkv, 3072*1024);
  combine_w<<<1024*1024/1024, 256, 0, stream>>>(o_b,    a_o,    lidx, Wo,   1024*1024);
  combine_w<<<4096*1024/1024, 256, 0, stream>>>(gate_b, a_gate, lidx, Wg,   4096*1024);
  combine_w<<<4096*1024/1024, 256, 0, stream>>>(up_b,   a_up,   lidx, Wu,   4096*1024);
  combine_w<<<4096*1024/1024, 256, 0, stream>>>(down_b, a_down, lidx, Wd,   1024*4096);

  rmsnorm_k<<<2048, 256, 0, stream>>>(x, n1w, gamma, beta, hbuf);
  gemm_bt<0><<<dim3(24,16), 256, 0, stream>>>(hbuf, Wqkv, 2048, 3072, 1024,
                                              nullptr, qkvb, nullptr, nullptr, nullptr, nullptr);
  attn_k<<<dim3(16,32), 256, 0, stream>>>(qkvb, attn);
  gemm_bt<1><<<dim3(8,16), 256, 0, stream>>>(attn, Wo, 2048, 1024, 1024,
                                             xat, nullptr, x, nullptr, nullptr, nullptr);
  rmsnorm_k<<<2048, 256, 0, stream>>>(xat, n2w, gamma, beta, h2);
  gemm_bt<0><<<dim3(32,16), 256, 0, stream>>>(h2, Wg, 2048, 4096, 1024,
                                              nullptr, gate, nullptr, nullptr, nullptr, nullptr);
  gemm_bt<3><<<dim3(32,16), 256, 0, stream>>>(h2, Wu, 2048, 4096, 1024,
                                              nullptr, act, nullptr, nullptr, gate, nullptr);
  gemm_bt<4><<<dim3(8,16), 256, 0, stream>>>(act, Wd, 2048, 1024, 4096,
                                             out, nullptr, x, xat, nullptr, iscale);
}

// Round 2
// 309.711 us; speedup vs baseline: 1.1185x; 1.1185x over previous
//
#include <hip/hip_runtime.h>
#include <hip/hip_bf16.h>
#include <math.h>

typedef __bf16 bf16;
typedef __bf16 bf16x8 __attribute__((ext_vector_type(8)));
typedef __bf16 bf16x4 __attribute__((ext_vector_type(4)));
typedef float f32x4 __attribute__((ext_vector_type(4)));

#define EPSc 1.1920929e-07f

static __device__ __forceinline__ void glds16(const void* g, void* l) {
  __builtin_amdgcn_global_load_lds((const __attribute__((address_space(1))) void*)g,
                                   (__attribute__((address_space(3))) void*)l, 16, 0, 0);
}

// ---------------- combine weights: out = sum_k alpha[lidx][k]*base[k] (bf16) ----------
__global__ __launch_bounds__(256) void combine_w(const float* __restrict__ base,
                                                 const float* __restrict__ alpha,
                                                 const int* __restrict__ lidx,
                                                 bf16* __restrict__ out, int n) {
  int li = lidx[0];
  float a0 = alpha[li*4+0], a1 = alpha[li*4+1], a2 = alpha[li*4+2], a3 = alpha[li*4+3];
  size_t i = (size_t)blockIdx.x * blockDim.x + threadIdx.x;
  const float4* b0 = (const float4*)base;
  const float4* b1 = (const float4*)(base + (size_t)n);
  const float4* b2 = (const float4*)(base + 2*(size_t)n);
  const float4* b3 = (const float4*)(base + 3*(size_t)n);
  float4 v0 = b0[i], v1 = b1[i], v2 = b2[i], v3 = b3[i];
  bf16x4 o;
  o[0] = (bf16)(a0*v0.x + a1*v1.x + a2*v2.x + a3*v3.x);
  o[1] = (bf16)(a0*v0.y + a1*v1.y + a2*v2.y + a3*v3.y);
  o[2] = (bf16)(a0*v0.z + a1*v1.z + a2*v2.z + a3*v3.z);
  o[3] = (bf16)(a0*v0.w + a1*v1.w + a2*v2.w + a3*v3.w);
  *(bf16x4*)&out[i*4] = o;
}

// ---------------- rmsnorm: out = x*rsqrt(mean(x^2)+eps)*w*gamma + beta (bf16) --------
__global__ __launch_bounds__(256) void rmsnorm_k(const float* __restrict__ x,
                                                 const float* __restrict__ w,
                                                 const float* __restrict__ gamma,
                                                 const float* __restrict__ beta,
                                                 bf16* __restrict__ out) {
  int row = blockIdx.x, t = threadIdx.x;
  const float4* xr = (const float4*)(x + (size_t)row*1024);
  float4 v = xr[t];
  float ss = v.x*v.x + v.y*v.y + v.z*v.z + v.w*v.w;
  #pragma unroll
  for (int off = 32; off > 0; off >>= 1) ss += __shfl_down(ss, off, 64);
  __shared__ float red[4];
  if ((t & 63) == 0) red[t >> 6] = ss;
  __syncthreads();
  float tot = red[0] + red[1] + red[2] + red[3];
  float r = rsqrtf(tot * (1.0f/1024.0f) + EPSc);
  float4 wv = ((const float4*)w)[t];
  float4 gv = ((const float4*)gamma)[t];
  float4 bv = ((const float4*)beta)[t];
  bf16x4 o;
  o[0] = (bf16)(v.x*r*wv.x*gv.x + bv.x);
  o[1] = (bf16)(v.y*r*wv.y*gv.y + bv.y);
  o[2] = (bf16)(v.z*r*wv.z*gv.z + bv.z);
  o[3] = (bf16)(v.w*r*wv.w*gv.w + bv.w);
  *(bf16x4*)&out[(size_t)row*1024 + t*4] = o;
}

// ---------------- GEMM: C[M,N] = A[M,K] * B[N,K]^T, bf16 in, fp32 acc ----------------
// Double-buffered LDS, prefetch-ahead (T3-minimum), XCD-swizzled 1D grid (T1).
// EP: 0 = store bf16; 1 = fp32 + auxf residual; 3 = silu(auxb)*acc -> bf16;
//     4 = out = x + (x_attn + acc - x)*iter_scale (fp32)
template<int EP>
__global__ __launch_bounds__(256)
void gemm_bt(const bf16* __restrict__ A, const bf16* __restrict__ Bw,
             int M, int N, int K, int gx,
             float* __restrict__ outf, bf16* __restrict__ outb,
             const float* __restrict__ auxf, const float* __restrict__ auxf2,
             const bf16* __restrict__ auxb, const float* __restrict__ iscale) {
  __shared__ __align__(16) bf16 As[2][128*64];
  __shared__ __align__(16) bf16 Bs[2][128*64];
  const int nwg = gridDim.x;
  const int orig = blockIdx.x;
  const int wg = (orig & 7) * (nwg >> 3) + (orig >> 3);   // nwg % 8 == 0 for all our grids
  const int tn0 = (wg % gx) * 128, tm0 = (wg / gx) * 128;
  const int tid = threadIdx.x, wave = tid >> 6, lane = tid & 63;
  const int lr = lane & 15, lg = lane >> 4;
  const int wr = wave >> 1, wc = wave & 1;
  f32x4 acc[4][4] = {};
  const int rs = lane >> 3, cs = (lane & 7) * 8;

  const bf16* Abase = A + (size_t)tm0 * K;
  const bf16* Bbase = Bw + (size_t)tn0 * K;

  auto stage = [&](bf16* as, bf16* bs, int k0) {
    #pragma unroll
    for (int j = 0; j < 4; ++j) {
      int chunk = wave*4 + j;
      int r = chunk*8 + rs;
      glds16(Abase + (size_t)r*K + k0 + cs, as + chunk*512 + lane*8);
      glds16(Bbase + (size_t)r*K + k0 + cs, bs + chunk*512 + lane*8);
    }
  };
  auto comp = [&](const bf16* as, const bf16* bs) {
    #pragma unroll
    for (int kk = 0; kk < 2; ++kk) {
      bf16x8 av[4], bv[4];
      #pragma unroll
      for (int m = 0; m < 4; ++m) av[m] = *(const bf16x8*)&as[(wr*64 + m*16 + lr)*64 + kk*32 + lg*8];
      #pragma unroll
      for (int n = 0; n < 4; ++n) bv[n] = *(const bf16x8*)&bs[(wc*64 + n*16 + lr)*64 + kk*32 + lg*8];
      #pragma unroll
      for (int m = 0; m < 4; ++m)
        #pragma unroll
        for (int n = 0; n < 4; ++n)
          acc[m][n] = __builtin_amdgcn_mfma_f32_16x16x32_bf16(av[m], bv[n], acc[m][n], 0, 0, 0);
    }
  };

  bf16 *a0 = As[0], *a1 = As[1], *b0 = Bs[0], *b1 = Bs[1];
  stage(a0, b0, 0);
  __syncthreads();                       // drains vmcnt(0): buf0 ready
  for (int k0 = 64; k0 < K; k0 += 64) {
    stage(a1, b1, k0);                   // prefetch next tile; stays in flight over compute
    comp(a0, b0);
    __syncthreads();                     // vmcnt(0)+lgkmcnt(0): next buf ready, cur buf consumed
    bf16* t;
    t = a0; a0 = a1; a1 = t;
    t = b0; b0 = b1; b1 = t;
  }
  comp(a0, b0);

  float its = 0.f;
  if constexpr (EP == 4) its = iscale[0];
  #pragma unroll
  for (int m = 0; m < 4; ++m)
    #pragma unroll
    for (int n = 0; n < 4; ++n)
      #pragma unroll
      for (int i = 0; i < 4; ++i) {
        int row = tm0 + wr*64 + m*16 + lg*4 + i;
        int col = tn0 + wc*64 + n*16 + lr;
        size_t idx = (size_t)row * N + col;
        float v = acc[m][n][i];
        if constexpr (EP == 0) outb[idx] = (bf16)v;
        else if constexpr (EP == 1) outf[idx] = auxf[idx] + v;
        else if constexpr (EP == 3) {
          float g = (float)auxb[idx];
          float s = g / (1.f + __expf(-g));
          outb[idx] = (bf16)(s * v);
        } else if constexpr (EP == 4) {
          float xv = auxf[idx], xa = auxf2[idx];
          outf[idx] = xv + (xa + v - xv) * its;
        }
      }
}

// ---------------- flash attention, causal, H=16 T=2048 HD=64 -------------------------
// qkv: [T][3072] bf16 (q|k|v per head blocks of 64). out: [T][1024] bf16
__global__ __launch_bounds__(256)
void attn_k(const bf16* __restrict__ qkv, bf16* __restrict__ out) {
  const int h = blockIdx.x, qb = blockIdx.y;
  const int tid = threadIdx.x, wave = tid >> 6, lane = tid & 63;
  const int lr = lane & 15, lg = lane >> 4;
  const int q0 = qb * 64;
  __shared__ __align__(16) bf16 Ks[64*72];
  __shared__ __align__(16) bf16 Vt[64*72];
  __shared__ __align__(16) bf16 Ps[4][16*72];

  bf16x8 qf[2];
  {
    const bf16* qrow = qkv + (size_t)(q0 + wave*16 + lr)*3072 + h*64;
    qf[0] = *(const bf16x8*)(qrow + lg*8);
    qf[1] = *(const bf16x8*)(qrow + 32 + lg*8);
  }
  f32x4 o[4] = {};
  float mrow[4], lrow[4];
  #pragma unroll
  for (int i = 0; i < 4; ++i) { mrow[i] = -__builtin_inff(); lrow[i] = 0.f; }

  for (int t = 0; t <= qb; ++t) {
    const int kv0 = t * 64;
    __syncthreads();
    #pragma unroll
    for (int j = 0; j < 2; ++j) {
      int idx = tid + j*256;
      int r = idx >> 3, c = (idx & 7) << 3;
      bf16x8 k8 = *(const bf16x8*)(qkv + (size_t)(kv0 + r)*3072 + 1024 + h*64 + c);
      *(bf16x8*)&Ks[r*72 + c] = k8;
      bf16x8 v8 = *(const bf16x8*)(qkv + (size_t)(kv0 + r)*3072 + 2048 + h*64 + c);
      #pragma unroll
      for (int e = 0; e < 8; ++e) Vt[(c + e)*72 + r] = v8[e];
    }
    __syncthreads();

    f32x4 s[4] = {};
    #pragma unroll
    for (int n = 0; n < 4; ++n) {
      bf16x8 k0f = *(const bf16x8*)&Ks[(n*16 + lr)*72 + lg*8];
      s[n] = __builtin_amdgcn_mfma_f32_16x16x32_bf16(qf[0], k0f, s[n], 0, 0, 0);
      bf16x8 k1f = *(const bf16x8*)&Ks[(n*16 + lr)*72 + 32 + lg*8];
      s[n] = __builtin_amdgcn_mfma_f32_16x16x32_bf16(qf[1], k1f, s[n], 0, 0, 0);
    }
    const int qbase = q0 + wave*16 + lg*4;
    #pragma unroll
    for (int n = 0; n < 4; ++n)
      #pragma unroll
      for (int i = 0; i < 4; ++i) {
        float sv = s[n][i] * 0.125f;
        s[n][i] = (kv0 + n*16 + lr <= qbase + i) ? sv : -__builtin_inff();
      }
    float mnew[4], fac[4], rsum[4];
    #pragma unroll
    for (int i = 0; i < 4; ++i) mnew[i] = fmaxf(fmaxf(s[0][i], s[1][i]), fmaxf(s[2][i], s[3][i]));
    #pragma unroll
    for (int i = 0; i < 4; ++i)
      #pragma unroll
      for (int off = 1; off < 16; off <<= 1) mnew[i] = fmaxf(mnew[i], __shfl_xor(mnew[i], off, 64));
    #pragma unroll
    for (int i = 0; i < 4; ++i) {
      float mt = fmaxf(mrow[i], mnew[i]);
      fac[i] = __expf(mrow[i] - mt);
      mrow[i] = mt;
    }
    #pragma unroll
    for (int n = 0; n < 4; ++n)
      #pragma unroll
      for (int i = 0; i < 4; ++i) s[n][i] = __expf(s[n][i] - mrow[i]);
    #pragma unroll
    for (int i = 0; i < 4; ++i) rsum[i] = s[0][i] + s[1][i] + s[2][i] + s[3][i];
    #pragma unroll
    for (int i = 0; i < 4; ++i)
      #pragma unroll
      for (int off = 1; off < 16; off <<= 1) rsum[i] += __shfl_xor(rsum[i], off, 64);
    #pragma unroll
    for (int i = 0; i < 4; ++i) lrow[i] = lrow[i]*fac[i] + rsum[i];
    #pragma unroll
    for (int nd = 0; nd < 4; ++nd)
      #pragma unroll
      for (int i = 0; i < 4; ++i) o[nd][i] *= fac[i];
    #pragma unroll
    for (int n = 0; n < 4; ++n)
      #pragma unroll
      for (int i = 0; i < 4; ++i) Ps[wave][(lg*4 + i)*72 + n*16 + lr] = (bf16)s[n][i];
    asm volatile("s_waitcnt lgkmcnt(0)" ::: "memory");
    #pragma unroll
    for (int kk = 0; kk < 2; ++kk) {
      bf16x8 pf = *(const bf16x8*)&Ps[wave][lr*72 + kk*32 + lg*8];
      #pragma unroll
      for (int nd = 0; nd < 4; ++nd) {
        bf16x8 vf = *(const bf16x8*)&Vt[(nd*16 + lr)*72 + kk*32 + lg*8];
        o[nd] = __builtin_amdgcn_mfma_f32_16x16x32_bf16(pf, vf, o[nd], 0, 0, 0);
      }
    }
  }
  #pragma unroll
  for (int i = 0; i < 4; ++i) {
    float inv = 1.f / lrow[i];
    #pragma unroll
    for (int nd = 0; nd < 4; ++nd)
      out[(size_t)(q0 + wave*16 + lg*4 + i)*1024 + h*64 + nd*16 + lr] = (bf16)(o[nd][i]*inv);
  }
}

extern "C" void kernel_launch(void* const* d_in, const int* in_sizes, int n_in,
                              void* d_out, int out_size, void* d_ws, size_t ws_size,
                              hipStream_t stream) {
  const float* x        = (const float*)d_in[0];
  const float* gamma    = (const float*)d_in[1];
  const float* beta     = (const float*)d_in[2];
  const float* iscale   = (const float*)d_in[3];
  const float* qkv_b    = (const float*)d_in[4];
  const float* o_b      = (const float*)d_in[5];
  const float* gate_b   = (const float*)d_in[6];
  const float* up_b     = (const float*)d_in[7];
  const float* down_b   = (const float*)d_in[8];
  const float* a_qkv    = (const float*)d_in[9];
  const float* a_o      = (const float*)d_in[10];
  const float* a_gate   = (const float*)d_in[11];
  const float* a_up     = (const float*)d_in[12];
  const float* a_down   = (const float*)d_in[13];
  const float* n1w      = (const float*)d_in[14];
  const float* n2w      = (const float*)d_in[15];
  const int*   lidx     = (const int*)d_in[16];

  char* p = (char*)d_ws;
  auto alloc = [&](size_t bytes) { char* r = p; p += (bytes + 255) & ~(size_t)255; return r; };
  bf16*  Wqkv = (bf16*)alloc((size_t)3072*1024*2);
  bf16*  Wo   = (bf16*)alloc((size_t)1024*1024*2);
  bf16*  Wg   = (bf16*)alloc((size_t)4096*1024*2);
  bf16*  Wu   = (bf16*)alloc((size_t)4096*1024*2);
  bf16*  Wd   = (bf16*)alloc((size_t)1024*4096*2);
  bf16*  hbuf = (bf16*)alloc((size_t)2048*1024*2);
  bf16*  qkvb = (bf16*)alloc((size_t)2048*3072*2);
  bf16*  attn = (bf16*)alloc((size_t)2048*1024*2);
  float* xat  = (float*)alloc((size_t)2048*1024*4);
  bf16*  h2   = (bf16*)alloc((size_t)2048*1024*2);
  bf16*  gate = (bf16*)alloc((size_t)2048*4096*2);
  bf16*  act  = (bf16*)alloc((size_t)2048*4096*2);
  float* out  = (float*)d_out;

  combine_w<<<3072*1024/1024, 256, 0, stream>>>(qkv_b,  a_qkv,  lidx, Wqkv, 3072*1024);
  combine_w<<<1024*1024/1024, 256, 0, stream>>>(o_b,    a_o,    lidx, Wo,   1024*1024);
  combine_w<<<4096*1024/1024, 256, 0, stream>>>(gate_b, a_gate, lidx, Wg,   4096*1024);
  combine_w<<<4096*1024/1024, 256, 0, stream>>>(up_b,   a_up,   lidx, Wu,   4096*1024);
  combine_w<<<4096*1024/1024, 256, 0, stream>>>(down_b, a_down, lidx, Wd,   1024*4096);

  rmsnorm_k<<<2048, 256, 0, stream>>>(x, n1w, gamma, beta, hbuf);
  gemm_bt<0><<<24*16, 256, 0, stream>>>(hbuf, Wqkv, 2048, 3072, 1024, 24,
                                        nullptr, qkvb, nullptr, nullptr, nullptr, nullptr);
  attn_k<<<dim3(16,32), 256, 0, stream>>>(qkvb, attn);
  gemm_bt<1><<<8*16, 256, 0, stream>>>(attn, Wo, 2048, 1024, 1024, 8,
                                       xat, nullptr, x, nullptr, nullptr, nullptr);
  rmsnorm_k<<<2048, 256, 0, stream>>>(xat, n2w, gamma, beta, h2);
  gemm_bt<0><<<32*16, 256, 0, stream>>>(h2, Wg, 2048, 4096, 1024, 32,
                                        nullptr, gate, nullptr, nullptr, nullptr, nullptr);
  gemm_bt<3><<<32*16, 256, 0, stream>>>(h2, Wu, 2048, 4096, 1024, 32,
                                        nullptr, act, nullptr, nullptr, gate, nullptr);
  gemm_bt<4><<<8*16, 256, 0, stream>>>(act, Wd, 2048, 1024, 4096, 8,
                                       out, nullptr, x, xat, nullptr, iscale);
}

// Round 3
// 272.733 us; speedup vs baseline: 1.2701x; 1.1356x over previous
//
#include <hip/hip_runtime.h>
#include <hip/hip_bf16.h>
#include <math.h>

typedef __bf16 bf16;
typedef __bf16 bf16x8 __attribute__((ext_vector_type(8)));
typedef __bf16 bf16x4 __attribute__((ext_vector_type(4)));
typedef float f32x4 __attribute__((ext_vector_type(4)));

#define EPSc 1.1920929e-07f
#define LOG2E 1.44269504f

static __device__ __forceinline__ void glds16(const void* g, void* l) {
  __builtin_amdgcn_global_load_lds((const __attribute__((address_space(1))) void*)g,
                                   (__attribute__((address_space(3))) void*)l, 16, 0, 0);
}

// ---------------- combine weights: out = sum_k alpha[lidx][k]*base[k] (bf16) ----------
__global__ __launch_bounds__(256) void combine_w(const float* __restrict__ base,
                                                 const float* __restrict__ alpha,
                                                 const int* __restrict__ lidx,
                                                 bf16* __restrict__ out, int n) {
  int li = lidx[0];
  float a0 = alpha[li*4+0], a1 = alpha[li*4+1], a2 = alpha[li*4+2], a3 = alpha[li*4+3];
  size_t i = (size_t)blockIdx.x * blockDim.x + threadIdx.x;
  const float4* b0 = (const float4*)base;
  const float4* b1 = (const float4*)(base + (size_t)n);
  const float4* b2 = (const float4*)(base + 2*(size_t)n);
  const float4* b3 = (const float4*)(base + 3*(size_t)n);
  float4 v0 = b0[i], v1 = b1[i], v2 = b2[i], v3 = b3[i];
  bf16x4 o;
  o[0] = (bf16)(a0*v0.x + a1*v1.x + a2*v2.x + a3*v3.x);
  o[1] = (bf16)(a0*v0.y + a1*v1.y + a2*v2.y + a3*v3.y);
  o[2] = (bf16)(a0*v0.z + a1*v1.z + a2*v2.z + a3*v3.z);
  o[3] = (bf16)(a0*v0.w + a1*v1.w + a2*v2.w + a3*v3.w);
  *(bf16x4*)&out[i*4] = o;
}

// ---- combine gate+up interleaved by 16-row groups: Wgu row r: t=r>>5,w=r&31 ----
//      f = t*16 + (w&15); gate if w<16 else up.  Wgu: [8192][1024] bf16
__global__ __launch_bounds__(256) void combine_gu(const float* __restrict__ gate_b,
                                                  const float* __restrict__ up_b,
                                                  const float* __restrict__ a_gate,
                                                  const float* __restrict__ a_up,
                                                  const int* __restrict__ lidx,
                                                  bf16* __restrict__ out) {
  int li = lidx[0];
  size_t i4 = (size_t)blockIdx.x * blockDim.x + threadIdx.x;
  size_t flat = i4 * 4;
  int r = (int)(flat >> 10), c = (int)(flat & 1023);
  int t = r >> 5, w = r & 31;
  int f = (t << 4) + (w & 15);
  const float* base = (w < 16) ? gate_b : up_b;
  const float* al   = (w < 16) ? a_gate : a_up;
  float a0 = al[li*4+0], a1 = al[li*4+1], a2 = al[li*4+2], a3 = al[li*4+3];
  const size_t stride = (size_t)4096 * 1024;
  const float4* s0 = (const float4*)(base + (size_t)f*1024 + c);
  const float4* s1 = (const float4*)(base + stride   + (size_t)f*1024 + c);
  const float4* s2 = (const float4*)(base + stride*2 + (size_t)f*1024 + c);
  const float4* s3 = (const float4*)(base + stride*3 + (size_t)f*1024 + c);
  float4 v0 = *s0, v1 = *s1, v2 = *s2, v3 = *s3;
  bf16x4 o;
  o[0] = (bf16)(a0*v0.x + a1*v1.x + a2*v2.x + a3*v3.x);
  o[1] = (bf16)(a0*v0.y + a1*v1.y + a2*v2.y + a3*v3.y);
  o[2] = (bf16)(a0*v0.z + a1*v1.z + a2*v2.z + a3*v3.z);
  o[3] = (bf16)(a0*v0.w + a1*v1.w + a2*v2.w + a3*v3.w);
  *(bf16x4*)&out[flat] = o;
}

// ---------------- rmsnorm: out = x*rsqrt(mean(x^2)+eps)*w*gamma + beta (bf16) --------
__global__ __launch_bounds__(256) void rmsnorm_k(const float* __restrict__ x,
                                                 const float* __restrict__ w,
                                                 const float* __restrict__ gamma,
                                                 const float* __restrict__ beta,
                                                 bf16* __restrict__ out) {
  int row = blockIdx.x, t = threadIdx.x;
  const float4* xr = (const float4*)(x + (size_t)row*1024);
  float4 v = xr[t];
  float ss = v.x*v.x + v.y*v.y + v.z*v.z + v.w*v.w;
  #pragma unroll
  for (int off = 32; off > 0; off >>= 1) ss += __shfl_down(ss, off, 64);
  __shared__ float red[4];
  if ((t & 63) == 0) red[t >> 6] = ss;
  __syncthreads();
  float tot = red[0] + red[1] + red[2] + red[3];
  float r = rsqrtf(tot * (1.0f/1024.0f) + EPSc);
  float4 wv = ((const float4*)w)[t];
  float4 gv = ((const float4*)gamma)[t];
  float4 bv = ((const float4*)beta)[t];
  bf16x4 o;
  o[0] = (bf16)(v.x*r*wv.x*gv.x + bv.x);
  o[1] = (bf16)(v.y*r*wv.y*gv.y + bv.y);
  o[2] = (bf16)(v.z*r*wv.z*gv.z + bv.z);
  o[3] = (bf16)(v.w*r*wv.w*gv.w + bv.w);
  *(bf16x4*)&out[(size_t)row*1024 + t*4] = o;
}

// ---------------- GEMM: C[M,N] = A[M,K] * B[N,K]^T, bf16 in, fp32 acc ----------------
// BM=128 fixed; BN = NTW*32 (NTW = n-tiles per wave, 2 or 4). Double-buffered LDS,
// prefetch-ahead, XCD-swizzled 1D grid.
// EP: 0 = store bf16; 1 = fp32 + auxf residual; 4 = x + (x_attn + acc - x)*iter_scale;
//     5 = fused silu(gate)*up -> bf16 (gate/up interleaved in 16-col pairs)
template<int EP, int NTW>
__global__ __launch_bounds__(256)
void gemm_bt(const bf16* __restrict__ A, const bf16* __restrict__ Bw,
             int M, int N, int K, int gx,
             float* __restrict__ outf, bf16* __restrict__ outb,
             const float* __restrict__ auxf, const float* __restrict__ auxf2,
             const float* __restrict__ iscale) {
  constexpr int BN = NTW * 32;
  __shared__ __align__(16) bf16 As[2][128*64];
  __shared__ __align__(16) bf16 Bs[2][BN*64];
  const int nwg = gridDim.x;
  const int orig = blockIdx.x;
  const int wg = (orig & 7) * (nwg >> 3) + (orig >> 3);   // nwg % 8 == 0 for all our grids
  const int tn0 = (wg % gx) * BN, tm0 = (wg / gx) * 128;
  const int tid = threadIdx.x, wave = tid >> 6, lane = tid & 63;
  const int lr = lane & 15, lg = lane >> 4;
  const int wr = wave >> 1, wc = wave & 1;
  f32x4 acc[4][NTW] = {};
  const int rs = lane >> 3, cs = (lane & 7) * 8;

  const bf16* Abase = A + (size_t)tm0 * K;
  const bf16* Bbase = Bw + (size_t)tn0 * K;

  auto stage = [&](bf16* as, bf16* bs, int k0) {
    #pragma unroll
    for (int j = 0; j < 4; ++j) {
      int chunk = wave*4 + j;
      int r = chunk*8 + rs;
      glds16(Abase + (size_t)r*K + k0 + cs, as + chunk*512 + lane*8);
    }
    #pragma unroll
    for (int j = 0; j < NTW; ++j) {
      int chunk = wave*NTW + j;
      int r = chunk*8 + rs;
      glds16(Bbase + (size_t)r*K + k0 + cs, bs + chunk*512 + lane*8);
    }
  };
  auto comp = [&](const bf16* as, const bf16* bs) {
    #pragma unroll
    for (int kk = 0; kk < 2; ++kk) {
      bf16x8 av[4], bv[NTW];
      #pragma unroll
      for (int m = 0; m < 4; ++m) av[m] = *(const bf16x8*)&as[(wr*64 + m*16 + lr)*64 + kk*32 + lg*8];
      #pragma unroll
      for (int n = 0; n < NTW; ++n) bv[n] = *(const bf16x8*)&bs[(wc*NTW*16 + n*16 + lr)*64 + kk*32 + lg*8];
      #pragma unroll
      for (int m = 0; m < 4; ++m)
        #pragma unroll
        for (int n = 0; n < NTW; ++n)
          acc[m][n] = __builtin_amdgcn_mfma_f32_16x16x32_bf16(av[m], bv[n], acc[m][n], 0, 0, 0);
    }
  };

  bf16 *a0 = As[0], *a1 = As[1], *b0 = Bs[0], *b1 = Bs[1];
  stage(a0, b0, 0);
  __syncthreads();
  for (int k0 = 64; k0 < K; k0 += 64) {
    stage(a1, b1, k0);
    comp(a0, b0);
    __syncthreads();
    bf16* t;
    t = a0; a0 = a1; a1 = t;
    t = b0; b0 = b1; b1 = t;
  }
  comp(a0, b0);

  float its = 0.f;
  if constexpr (EP == 4) its = iscale[0];

  if constexpr (EP == 5) {
    // n pairs: (0,1),(2,3) -> gate,up for same f block of 16
    #pragma unroll
    for (int m = 0; m < 4; ++m)
      #pragma unroll
      for (int j = 0; j < NTW/2; ++j)
        #pragma unroll
        for (int i = 0; i < 4; ++i) {
          int row = tm0 + wr*64 + m*16 + lg*4 + i;
          int col = (tn0 >> 1) + wc*(NTW*8) + j*16 + lr;
          float g = acc[m][2*j][i], u = acc[m][2*j+1][i];
          float s = g / (1.f + __builtin_amdgcn_exp2f(-g * LOG2E));
          outb[(size_t)row * (N >> 1) + col] = (bf16)(s * u);
        }
  } else {
    #pragma unroll
    for (int m = 0; m < 4; ++m)
      #pragma unroll
      for (int n = 0; n < NTW; ++n)
        #pragma unroll
        for (int i = 0; i < 4; ++i) {
          int row = tm0 + wr*64 + m*16 + lg*4 + i;
          int col = tn0 + wc*NTW*16 + n*16 + lr;
          size_t idx = (size_t)row * N + col;
          float v = acc[m][n][i];
          if constexpr (EP == 0) outb[idx] = (bf16)v;
          else if constexpr (EP == 1) outf[idx] = auxf[idx] + v;
          else if constexpr (EP == 4) {
            float xv = auxf[idx], xa = auxf2[idx];
            outf[idx] = xv + (xa + v - xv) * its;
          }
        }
  }
}

// ---------------- flash attention, causal, H=16 T=2048 HD=64 -------------------------
// qkv: [T][3072] bf16 (q|k|v per head blocks of 64). out: [T][1024] bf16
// LPT 1D grid: longest q-blocks dispatched first; h spread so each XCD sees 2 heads.
__global__ __launch_bounds__(256)
void attn_k(const bf16* __restrict__ qkv, bf16* __restrict__ out) {
  const int bid = blockIdx.x;
  const int qb = 31 - (bid >> 4);
  const int h = (bid & 7) + 8 * ((bid >> 3) & 1);
  const int tid = threadIdx.x, wave = tid >> 6, lane = tid & 63;
  const int lr = lane & 15, lg = lane >> 4;
  const int q0 = qb * 64;
  __shared__ __align__(16) bf16 Ks[2][64*72];
  __shared__ __align__(16) bf16 Vt[2][64*66];
  __shared__ __align__(16) bf16 Ps[4][16*68];

  bf16x8 qf[2];
  {
    const bf16* qrow = qkv + (size_t)(q0 + wave*16 + lr)*3072 + h*64;
    qf[0] = *(const bf16x8*)(qrow + lg*8);
    qf[1] = *(const bf16x8*)(qrow + 32 + lg*8);
  }
  f32x4 o[4] = {};
  float mrow[4], lrow[4];
  #pragma unroll
  for (int i = 0; i < 4; ++i) { mrow[i] = -__builtin_inff(); lrow[i] = 0.f; }

  const int r0 = tid >> 3, r1 = (tid + 256) >> 3;
  const int c0 = (tid & 7) << 3;
  const bf16* kb = qkv + 1024 + h*64 + c0;
  const bf16* vb = qkv + 2048 + h*64 + c0;

  bf16x8 kreg[2], vreg[2];
  auto stage_load = [&](int kv0) {
    kreg[0] = *(const bf16x8*)(kb + (size_t)(kv0 + r0)*3072);
    kreg[1] = *(const bf16x8*)(kb + (size_t)(kv0 + r1)*3072);
    vreg[0] = *(const bf16x8*)(vb + (size_t)(kv0 + r0)*3072);
    vreg[1] = *(const bf16x8*)(vb + (size_t)(kv0 + r1)*3072);
  };
  auto stage_write = [&](int buf) {
    *(bf16x8*)&Ks[buf][r0*72 + c0] = kreg[0];
    *(bf16x8*)&Ks[buf][r1*72 + c0] = kreg[1];
    #pragma unroll
    for (int e = 0; e < 8; ++e) Vt[buf][(c0 + e)*66 + r0] = vreg[0][e];
    #pragma unroll
    for (int e = 0; e < 8; ++e) Vt[buf][(c0 + e)*66 + r1] = vreg[1][e];
  };

  stage_load(0);
  stage_write(0);
  __syncthreads();
  int cur = 0;

  const float C = 0.125f * LOG2E;   // QK scale folded with log2(e): work in exp2 domain

  for (int t = 0; t <= qb; ++t) {
    const int kv0 = t * 64;
    if (t < qb) stage_load(kv0 + 64);       // async: loads in flight over compute

    f32x4 s[4] = {};
    #pragma unroll
    for (int n = 0; n < 4; ++n) {
      bf16x8 k0f = *(const bf16x8*)&Ks[cur][(n*16 + lr)*72 + lg*8];
      s[n] = __builtin_amdgcn_mfma_f32_16x16x32_bf16(qf[0], k0f, s[n], 0, 0, 0);
      bf16x8 k1f = *(const bf16x8*)&Ks[cur][(n*16 + lr)*72 + 32 + lg*8];
      s[n] = __builtin_amdgcn_mfma_f32_16x16x32_bf16(qf[1], k1f, s[n], 0, 0, 0);
    }
    const int qbase = q0 + wave*16 + lg*4;
    #pragma unroll
    for (int n = 0; n < 4; ++n)
      #pragma unroll
      for (int i = 0; i < 4; ++i) {
        float sv = s[n][i] * C;
        s[n][i] = (kv0 + n*16 + lr <= qbase + i) ? sv : -__builtin_inff();
      }
    float mnew[4], fac[4], rsum[4];
    #pragma unroll
    for (int i = 0; i < 4; ++i) mnew[i] = fmaxf(fmaxf(s[0][i], s[1][i]), fmaxf(s[2][i], s[3][i]));
    #pragma unroll
    for (int i = 0; i < 4; ++i)
      #pragma unroll
      for (int off = 1; off < 16; off <<= 1) mnew[i] = fmaxf(mnew[i], __shfl_xor(mnew[i], off, 64));
    #pragma unroll
    for (int i = 0; i < 4; ++i) {
      float mt = fmaxf(mrow[i], mnew[i]);
      fac[i] = __builtin_amdgcn_exp2f(mrow[i] - mt);   // exp2(-inf)=0 on first tile
      mrow[i] = mt;
    }
    #pragma unroll
    for (int n = 0; n < 4; ++n)
      #pragma unroll
      for (int i = 0; i < 4; ++i) s[n][i] = __builtin_amdgcn_exp2f(s[n][i] - mrow[i]);
    #pragma unroll
    for (int i = 0; i < 4; ++i) rsum[i] = s[0][i] + s[1][i] + s[2][i] + s[3][i];
    #pragma unroll
    for (int i = 0; i < 4; ++i)
      #pragma unroll
      for (int off = 1; off < 16; off <<= 1) rsum[i] += __shfl_xor(rsum[i], off, 64);
    #pragma unroll
    for (int i = 0; i < 4; ++i) lrow[i] = lrow[i]*fac[i] + rsum[i];
    #pragma unroll
    for (int nd = 0; nd < 4; ++nd)
      #pragma unroll
      for (int i = 0; i < 4; ++i) o[nd][i] *= fac[i];
    #pragma unroll
    for (int n = 0; n < 4; ++n)
      #pragma unroll
      for (int i = 0; i < 4; ++i) Ps[wave][(lg*4 + i)*68 + n*16 + lr] = (bf16)s[n][i];
    asm volatile("s_waitcnt lgkmcnt(0)" ::: "memory");
    #pragma unroll
    for (int kk = 0; kk < 2; ++kk) {
      bf16x8 pf = *(const bf16x8*)&Ps[wave][lr*68 + kk*32 + lg*8];
      #pragma unroll
      for (int nd = 0; nd < 4; ++nd) {
        bf16x8 vf = *(const bf16x8*)&Vt[cur][(nd*16 + lr)*66 + kk*32 + lg*8];
        o[nd] = __builtin_amdgcn_mfma_f32_16x16x32_bf16(pf, vf, o[nd], 0, 0, 0);
      }
    }
    if (t < qb) {
      stage_write(cur ^ 1);                 // other buffer: no race with current readers
      __syncthreads();                      // next buffer ready for all waves
      cur ^= 1;
    }
  }
  #pragma unroll
  for (int i = 0; i < 4; ++i) {
    float inv = 1.f / lrow[i];
    #pragma unroll
    for (int nd = 0; nd < 4; ++nd)
      out[(size_t)(q0 + wave*16 + lg*4 + i)*1024 + h*64 + nd*16 + lr] = (bf16)(o[nd][i]*inv);
  }
}

extern "C" void kernel_launch(void* const* d_in, const int* in_sizes, int n_in,
                              void* d_out, int out_size, void* d_ws, size_t ws_size,
                              hipStream_t stream) {
  const float* x        = (const float*)d_in[0];
  const float* gamma    = (const float*)d_in[1];
  const float* beta     = (const float*)d_in[2];
  const float* iscale   = (const float*)d_in[3];
  const float* qkv_b    = (const float*)d_in[4];
  const float* o_b      = (const float*)d_in[5];
  const float* gate_b   = (const float*)d_in[6];
  const float* up_b     = (const float*)d_in[7];
  const float* down_b   = (const float*)d_in[8];
  const float* a_qkv    = (const float*)d_in[9];
  const float* a_o      = (const float*)d_in[10];
  const float* a_gate   = (const float*)d_in[11];
  const float* a_up     = (const float*)d_in[12];
  const float* a_down   = (const float*)d_in[13];
  const float* n1w      = (const float*)d_in[14];
  const float* n2w      = (const float*)d_in[15];
  const int*   lidx     = (const int*)d_in[16];

  char* p = (char*)d_ws;
  auto alloc = [&](size_t bytes) { char* r = p; p += (bytes + 255) & ~(size_t)255; return r; };
  bf16*  Wqkv = (bf16*)alloc((size_t)3072*1024*2);
  bf16*  Wo   = (bf16*)alloc((size_t)1024*1024*2);
  bf16*  Wgu  = (bf16*)alloc((size_t)8192*1024*2);
  bf16*  Wd   = (bf16*)alloc((size_t)1024*4096*2);
  bf16*  hbuf = (bf16*)alloc((size_t)2048*1024*2);
  bf16*  qkvb = (bf16*)alloc((size_t)2048*3072*2);
  bf16*  attn = (bf16*)alloc((size_t)2048*1024*2);
  float* xat  = (float*)alloc((size_t)2048*1024*4);
  bf16*  h2   = (bf16*)alloc((size_t)2048*1024*2);
  bf16*  act  = (bf16*)alloc((size_t)2048*4096*2);
  float* out  = (float*)d_out;

  combine_w<<<3072, 256, 0, stream>>>(qkv_b,  a_qkv,  lidx, Wqkv, 3072*1024);
  combine_w<<<1024, 256, 0, stream>>>(o_b,    a_o,    lidx, Wo,   1024*1024);
  combine_gu<<<8192, 256, 0, stream>>>(gate_b, up_b, a_gate, a_up, lidx, Wgu);
  combine_w<<<4096, 256, 0, stream>>>(down_b, a_down, lidx, Wd,   1024*4096);

  rmsnorm_k<<<2048, 256, 0, stream>>>(x, n1w, gamma, beta, hbuf);
  gemm_bt<0,4><<<24*16, 256, 0, stream>>>(hbuf, Wqkv, 2048, 3072, 1024, 24,
                                          nullptr, qkvb, nullptr, nullptr, nullptr);
  attn_k<<<512, 256, 0, stream>>>(qkvb, attn);
  gemm_bt<1,2><<<16*16, 256, 0, stream>>>(attn, Wo, 2048, 1024, 1024, 16,
                                          xat, nullptr, x, nullptr, nullptr);
  rmsnorm_k<<<2048, 256, 0, stream>>>(xat, n2w, gamma, beta, h2);
  gemm_bt<5,4><<<64*16, 256, 0, stream>>>(h2, Wgu, 2048, 8192, 1024, 64,
                                          nullptr, act, nullptr, nullptr, nullptr);
  gemm_bt<4,2><<<16*16, 256, 0, stream>>>(act, Wd, 2048, 1024, 4096, 16,
                                          out, nullptr, x, xat, iscale);
}

// Round 4
// 225.272 us; speedup vs baseline: 1.5377x; 1.2107x over previous
//
#include <hip/hip_runtime.h>
#include <hip/hip_bf16.h>
#include <math.h>

typedef __bf16 bf16;
typedef __bf16 bf16x8 __attribute__((ext_vector_type(8)));
typedef __bf16 bf16x4 __attribute__((ext_vector_type(4)));
typedef float f32x4 __attribute__((ext_vector_type(4)));

#define EPSc 1.1920929e-07f
#define LOG2E 1.44269504f

static __device__ __forceinline__ void glds16(const void* g, void* l) {
  __builtin_amdgcn_global_load_lds((const __attribute__((address_space(1))) void*)g,
                                   (__attribute__((address_space(3))) void*)l, 16, 0, 0);
}

static __device__ __forceinline__ bf16x4 comb4(const float* b0, const float* b1,
                                               const float* b2, const float* b3,
                                               float a0, float a1, float a2, float a3) {
  float4 v0 = *(const float4*)b0, v1 = *(const float4*)b1;
  float4 v2 = *(const float4*)b2, v3 = *(const float4*)b3;
  bf16x4 o;
  o[0] = (bf16)(a0*v0.x + a1*v1.x + a2*v2.x + a3*v3.x);
  o[1] = (bf16)(a0*v0.y + a1*v1.y + a2*v2.y + a3*v3.y);
  o[2] = (bf16)(a0*v0.z + a1*v1.z + a2*v2.z + a3*v3.z);
  o[3] = (bf16)(a0*v0.w + a1*v1.w + a2*v2.w + a3*v3.w);
  return o;
}

// ---- prep1: fused combine_qkv + combine_o + rmsnorm1 (all independent) -------------
// bids [0,3072): Wqkv rows; [3072,4096): Wo rows; [4096,6144): rmsnorm rows
__global__ __launch_bounds__(256)
void prep1(const float* __restrict__ qkv_b, const float* __restrict__ a_qkv,
           const float* __restrict__ o_b,   const float* __restrict__ a_o,
           const float* __restrict__ x, const float* __restrict__ n1w,
           const float* __restrict__ gamma, const float* __restrict__ beta,
           const int* __restrict__ lidx,
           bf16* __restrict__ Wqkv, bf16* __restrict__ Wo, bf16* __restrict__ hbuf) {
  const int bid = blockIdx.x, tid = threadIdx.x;
  if (bid < 4096) {
    int li = lidx[0];
    const float* base; const float* al; bf16* out; size_t flat, n;
    if (bid < 3072) { base = qkv_b; al = a_qkv; out = Wqkv; flat = (size_t)bid << 10; n = (size_t)3072*1024; }
    else            { base = o_b;   al = a_o;   out = Wo;   flat = (size_t)(bid-3072) << 10; n = (size_t)1024*1024; }
    float a0 = al[li*4], a1 = al[li*4+1], a2 = al[li*4+2], a3 = al[li*4+3];
    size_t off = flat + tid*4;
    bf16x4 o = comb4(base+off, base+n+off, base+2*n+off, base+3*n+off, a0, a1, a2, a3);
    *(bf16x4*)&out[off] = o;
  } else {
    int row = bid - 4096, t = tid;
    const float4* xr = (const float4*)(x + (size_t)row*1024);
    float4 v = xr[t];
    float ss = v.x*v.x + v.y*v.y + v.z*v.z + v.w*v.w;
    #pragma unroll
    for (int off = 32; off > 0; off >>= 1) ss += __shfl_down(ss, off, 64);
    __shared__ float red[4];
    if ((t & 63) == 0) red[t >> 6] = ss;
    __syncthreads();
    float tot = red[0] + red[1] + red[2] + red[3];
    float r = rsqrtf(tot * (1.0f/1024.0f) + EPSc);
    float4 wv = ((const float4*)n1w)[t];
    float4 gv = ((const float4*)gamma)[t];
    float4 bv = ((const float4*)beta)[t];
    bf16x4 o;
    o[0] = (bf16)(v.x*r*wv.x*gv.x + bv.x);
    o[1] = (bf16)(v.y*r*wv.y*gv.y + bv.y);
    o[2] = (bf16)(v.z*r*wv.z*gv.z + bv.z);
    o[3] = (bf16)(v.w*r*wv.w*gv.w + bv.w);
    *(bf16x4*)&hbuf[(size_t)row*1024 + t*4] = o;
  }
}

// ---------------- rmsnorm (standalone, for norm2) ------------------------------------
__global__ __launch_bounds__(256) void rmsnorm_k(const float* __restrict__ x,
                                                 const float* __restrict__ w,
                                                 const float* __restrict__ gamma,
                                                 const float* __restrict__ beta,
                                                 bf16* __restrict__ out) {
  int row = blockIdx.x, t = threadIdx.x;
  const float4* xr = (const float4*)(x + (size_t)row*1024);
  float4 v = xr[t];
  float ss = v.x*v.x + v.y*v.y + v.z*v.z + v.w*v.w;
  #pragma unroll
  for (int off = 32; off > 0; off >>= 1) ss += __shfl_down(ss, off, 64);
  __shared__ float red[4];
  if ((t & 63) == 0) red[t >> 6] = ss;
  __syncthreads();
  float tot = red[0] + red[1] + red[2] + red[3];
  float r = rsqrtf(tot * (1.0f/1024.0f) + EPSc);
  float4 wv = ((const float4*)w)[t];
  float4 gv = ((const float4*)gamma)[t];
  float4 bv = ((const float4*)beta)[t];
  bf16x4 o;
  o[0] = (bf16)(v.x*r*wv.x*gv.x + bv.x);
  o[1] = (bf16)(v.y*r*wv.y*gv.y + bv.y);
  o[2] = (bf16)(v.z*r*wv.z*gv.z + bv.z);
  o[3] = (bf16)(v.w*r*wv.w*gv.w + bv.w);
  *(bf16x4*)&out[(size_t)row*1024 + t*4] = o;
}

// ---------------- GEMM: C[M,N] = A[M,K] * B[N,K]^T, bf16 in, fp32 acc ----------------
template<int EP, int NTW>
__global__ __launch_bounds__(256)
void gemm_bt(const bf16* __restrict__ A, const bf16* __restrict__ Bw,
             int M, int N, int K, int gx,
             float* __restrict__ outf, bf16* __restrict__ outb,
             const float* __restrict__ auxf, const float* __restrict__ auxf2,
             const float* __restrict__ iscale) {
  constexpr int BN = NTW * 32;
  __shared__ __align__(16) bf16 As[2][128*64];
  __shared__ __align__(16) bf16 Bs[2][BN*64];
  const int nwg = gridDim.x;
  const int orig = blockIdx.x;
  const int wg = (orig & 7) * (nwg >> 3) + (orig >> 3);
  const int tn0 = (wg % gx) * BN, tm0 = (wg / gx) * 128;
  const int tid = threadIdx.x, wave = tid >> 6, lane = tid & 63;
  const int lr = lane & 15, lg = lane >> 4;
  const int wr = wave >> 1, wc = wave & 1;
  f32x4 acc[4][NTW] = {};
  const int rs = lane >> 3, cs = (lane & 7) * 8;

  const bf16* Abase = A + (size_t)tm0 * K;
  const bf16* Bbase = Bw + (size_t)tn0 * K;

  auto stage = [&](bf16* as, bf16* bs, int k0) {
    #pragma unroll
    for (int j = 0; j < 4; ++j) {
      int chunk = wave*4 + j;
      int r = chunk*8 + rs;
      glds16(Abase + (size_t)r*K + k0 + cs, as + chunk*512 + lane*8);
    }
    #pragma unroll
    for (int j = 0; j < NTW; ++j) {
      int chunk = wave*NTW + j;
      int r = chunk*8 + rs;
      glds16(Bbase + (size_t)r*K + k0 + cs, bs + chunk*512 + lane*8);
    }
  };
  auto comp = [&](const bf16* as, const bf16* bs) {
    #pragma unroll
    for (int kk = 0; kk < 2; ++kk) {
      bf16x8 av[4], bv[NTW];
      #pragma unroll
      for (int m = 0; m < 4; ++m) av[m] = *(const bf16x8*)&as[(wr*64 + m*16 + lr)*64 + kk*32 + lg*8];
      #pragma unroll
      for (int n = 0; n < NTW; ++n) bv[n] = *(const bf16x8*)&bs[(wc*NTW*16 + n*16 + lr)*64 + kk*32 + lg*8];
      #pragma unroll
      for (int m = 0; m < 4; ++m)
        #pragma unroll
        for (int n = 0; n < NTW; ++n)
          acc[m][n] = __builtin_amdgcn_mfma_f32_16x16x32_bf16(av[m], bv[n], acc[m][n], 0, 0, 0);
    }
  };

  bf16 *a0 = As[0], *a1 = As[1], *b0 = Bs[0], *b1 = Bs[1];
  stage(a0, b0, 0);
  __syncthreads();
  for (int k0 = 64; k0 < K; k0 += 64) {
    stage(a1, b1, k0);
    comp(a0, b0);
    __syncthreads();
    bf16* t;
    t = a0; a0 = a1; a1 = t;
    t = b0; b0 = b1; b1 = t;
  }
  comp(a0, b0);

  float its = 0.f;
  if constexpr (EP == 4) its = iscale[0];

  if constexpr (EP == 5) {
    #pragma unroll
    for (int m = 0; m < 4; ++m)
      #pragma unroll
      for (int j = 0; j < NTW/2; ++j)
        #pragma unroll
        for (int i = 0; i < 4; ++i) {
          int row = tm0 + wr*64 + m*16 + lg*4 + i;
          int col = (tn0 >> 1) + wc*(NTW*8) + j*16 + lr;
          float g = acc[m][2*j][i], u = acc[m][2*j+1][i];
          float s = g / (1.f + __builtin_amdgcn_exp2f(-g * LOG2E));
          outb[(size_t)row * (N >> 1) + col] = (bf16)(s * u);
        }
  } else {
    #pragma unroll
    for (int m = 0; m < 4; ++m)
      #pragma unroll
      for (int n = 0; n < NTW; ++n)
        #pragma unroll
        for (int i = 0; i < 4; ++i) {
          int row = tm0 + wr*64 + m*16 + lg*4 + i;
          int col = tn0 + wc*NTW*16 + n*16 + lr;
          size_t idx = (size_t)row * N + col;
          float v = acc[m][n][i];
          if constexpr (EP == 0) outb[idx] = (bf16)v;
          else if constexpr (EP == 1) outf[idx] = auxf[idx] + v;
          else if constexpr (EP == 4) {
            float xv = auxf[idx], xa = auxf2[idx];
            outf[idx] = xv + (xa + v - xv) * its;
          }
        }
  }
}

// ---- mega-kernel: flash attention (bids 0..511) + gu/down weight combine (512..1023)
// Independent work overlapped: attn is latency-bound (~2% HBM), combine is pure BW.
__global__ __launch_bounds__(256)
void attn_mega(const bf16* __restrict__ qkv, bf16* __restrict__ out,
               const float* __restrict__ gate_b, const float* __restrict__ up_b,
               const float* __restrict__ down_b,
               const float* __restrict__ a_gate, const float* __restrict__ a_up,
               const float* __restrict__ a_down, const int* __restrict__ lidx,
               bf16* __restrict__ Wgu, bf16* __restrict__ Wd) {
  __shared__ __align__(16) bf16 Ks[2][64*72];
  __shared__ __align__(16) bf16 Vt[2][64*66];
  __shared__ __align__(16) bf16 Ps[4][16*68];
  const int bid = blockIdx.x;
  const int tid = threadIdx.x;

  if (bid >= 512) {
    // ---------------- combine path: 12288 row-chunks over 512 blocks --------------
    const int cb = bid - 512;
    int li = lidx[0];
    float g0 = a_gate[li*4], g1 = a_gate[li*4+1], g2 = a_gate[li*4+2], g3 = a_gate[li*4+3];
    float u0 = a_up[li*4],   u1 = a_up[li*4+1],   u2 = a_up[li*4+2],   u3 = a_up[li*4+3];
    float d0 = a_down[li*4], d1 = a_down[li*4+1], d2 = a_down[li*4+2], d3 = a_down[li*4+3];
    const size_t PS = (size_t)4096 * 1024;   // plane stride for gate/up/down bases
    for (int it = 0; it < 24; ++it) {
      int chunk = cb * 24 + it;
      if (chunk < 8192) {
        // Wgu row r, interleaved 16-row groups: f = (r>>5)*16 + (r&15); gate if (r&31)<16
        int r = chunk, w = r & 31;
        int f = ((r >> 5) << 4) + (w & 15);
        const float* base = (w < 16) ? gate_b : up_b;
        float a0 = (w < 16) ? g0 : u0, a1 = (w < 16) ? g1 : u1;
        float a2 = (w < 16) ? g2 : u2, a3 = (w < 16) ? g3 : u3;
        size_t src = (size_t)f*1024 + tid*4;
        bf16x4 o = comb4(base+src, base+PS+src, base+2*PS+src, base+3*PS+src, a0, a1, a2, a3);
        *(bf16x4*)&Wgu[((size_t)r << 10) + tid*4] = o;
      } else {
        size_t off = ((size_t)(chunk - 8192) << 10) + tid*4;
        bf16x4 o = comb4(down_b+off, down_b+PS+off, down_b+2*PS+off, down_b+3*PS+off, d0, d1, d2, d3);
        *(bf16x4*)&Wd[off] = o;
      }
    }
    return;
  }

  // ---------------- attention path: causal flash, H=16 T=2048 HD=64 ----------------
  const int qb = 31 - (bid >> 4);
  const int h = (bid & 7) + 8 * ((bid >> 3) & 1);
  const int wave = tid >> 6, lane = tid & 63;
  const int lr = lane & 15, lg = lane >> 4;
  const int q0 = qb * 64;

  bf16x8 qf[2];
  {
    const bf16* qrow = qkv + (size_t)(q0 + wave*16 + lr)*3072 + h*64;
    qf[0] = *(const bf16x8*)(qrow + lg*8);
    qf[1] = *(const bf16x8*)(qrow + 32 + lg*8);
  }
  f32x4 o[4] = {};
  float mrow[4], lrow[4];
  #pragma unroll
  for (int i = 0; i < 4; ++i) { mrow[i] = -__builtin_inff(); lrow[i] = 0.f; }

  const int r0 = tid >> 3, r1 = (tid + 256) >> 3;
  const int c0 = (tid & 7) << 3;
  const bf16* kb = qkv + 1024 + h*64 + c0;
  const bf16* vb = qkv + 2048 + h*64 + c0;

  bf16x8 kreg[2], vreg[2];
  auto stage_load = [&](int kv0) {
    kreg[0] = *(const bf16x8*)(kb + (size_t)(kv0 + r0)*3072);
    kreg[1] = *(const bf16x8*)(kb + (size_t)(kv0 + r1)*3072);
    vreg[0] = *(const bf16x8*)(vb + (size_t)(kv0 + r0)*3072);
    vreg[1] = *(const bf16x8*)(vb + (size_t)(kv0 + r1)*3072);
  };
  auto stage_write = [&](int buf) {
    *(bf16x8*)&Ks[buf][r0*72 + c0] = kreg[0];
    *(bf16x8*)&Ks[buf][r1*72 + c0] = kreg[1];
    #pragma unroll
    for (int e = 0; e < 8; ++e) Vt[buf][(c0 + e)*66 + r0] = vreg[0][e];
    #pragma unroll
    for (int e = 0; e < 8; ++e) Vt[buf][(c0 + e)*66 + r1] = vreg[1][e];
  };

  stage_load(0);
  stage_write(0);
  __syncthreads();
  int cur = 0;

  const float C = 0.125f * LOG2E;

  for (int t = 0; t <= qb; ++t) {
    const int kv0 = t * 64;
    if (t < qb) stage_load(kv0 + 64);

    f32x4 s[4] = {};
    __builtin_amdgcn_s_setprio(1);
    #pragma unroll
    for (int n = 0; n < 4; ++n) {
      bf16x8 k0f = *(const bf16x8*)&Ks[cur][(n*16 + lr)*72 + lg*8];
      s[n] = __builtin_amdgcn_mfma_f32_16x16x32_bf16(qf[0], k0f, s[n], 0, 0, 0);
      bf16x8 k1f = *(const bf16x8*)&Ks[cur][(n*16 + lr)*72 + 32 + lg*8];
      s[n] = __builtin_amdgcn_mfma_f32_16x16x32_bf16(qf[1], k1f, s[n], 0, 0, 0);
    }
    __builtin_amdgcn_s_setprio(0);
    const int qbase = q0 + wave*16 + lg*4;
    #pragma unroll
    for (int n = 0; n < 4; ++n)
      #pragma unroll
      for (int i = 0; i < 4; ++i) {
        float sv = s[n][i] * C;
        s[n][i] = (kv0 + n*16 + lr <= qbase + i) ? sv : -__builtin_inff();
      }
    float mnew[4], fac[4], rsum[4];
    #pragma unroll
    for (int i = 0; i < 4; ++i) mnew[i] = fmaxf(fmaxf(s[0][i], s[1][i]), fmaxf(s[2][i], s[3][i]));
    #pragma unroll
    for (int i = 0; i < 4; ++i)
      #pragma unroll
      for (int off = 1; off < 16; off <<= 1) mnew[i] = fmaxf(mnew[i], __shfl_xor(mnew[i], off, 64));
    #pragma unroll
    for (int i = 0; i < 4; ++i) {
      float mt = fmaxf(mrow[i], mnew[i]);
      fac[i] = __builtin_amdgcn_exp2f(mrow[i] - mt);
      mrow[i] = mt;
    }
    #pragma unroll
    for (int n = 0; n < 4; ++n)
      #pragma unroll
      for (int i = 0; i < 4; ++i) s[n][i] = __builtin_amdgcn_exp2f(s[n][i] - mrow[i]);
    #pragma unroll
    for (int i = 0; i < 4; ++i) rsum[i] = s[0][i] + s[1][i] + s[2][i] + s[3][i];
    #pragma unroll
    for (int i = 0; i < 4; ++i)
      #pragma unroll
      for (int off = 1; off < 16; off <<= 1) rsum[i] += __shfl_xor(rsum[i], off, 64);
    #pragma unroll
    for (int i = 0; i < 4; ++i) lrow[i] = lrow[i]*fac[i] + rsum[i];
    #pragma unroll
    for (int nd = 0; nd < 4; ++nd)
      #pragma unroll
      for (int i = 0; i < 4; ++i) o[nd][i] *= fac[i];
    #pragma unroll
    for (int n = 0; n < 4; ++n)
      #pragma unroll
      for (int i = 0; i < 4; ++i) Ps[wave][(lg*4 + i)*68 + n*16 + lr] = (bf16)s[n][i];
    asm volatile("s_waitcnt lgkmcnt(0)" ::: "memory");
    __builtin_amdgcn_s_setprio(1);
    #pragma unroll
    for (int kk = 0; kk < 2; ++kk) {
      bf16x8 pf = *(const bf16x8*)&Ps[wave][lr*68 + kk*32 + lg*8];
      #pragma unroll
      for (int nd = 0; nd < 4; ++nd) {
        bf16x8 vf = *(const bf16x8*)&Vt[cur][(nd*16 + lr)*66 + kk*32 + lg*8];
        o[nd] = __builtin_amdgcn_mfma_f32_16x16x32_bf16(pf, vf, o[nd], 0, 0, 0);
      }
    }
    __builtin_amdgcn_s_setprio(0);
    if (t < qb) {
      stage_write(cur ^ 1);
      __syncthreads();
      cur ^= 1;
    }
  }
  #pragma unroll
  for (int i = 0; i < 4; ++i) {
    float inv = 1.f / lrow[i];
    #pragma unroll
    for (int nd = 0; nd < 4; ++nd)
      out[(size_t)(q0 + wave*16 + lg*4 + i)*1024 + h*64 + nd*16 + lr] = (bf16)(o[nd][i]*inv);
  }
}

extern "C" void kernel_launch(void* const* d_in, const int* in_sizes, int n_in,
                              void* d_out, int out_size, void* d_ws, size_t ws_size,
                              hipStream_t stream) {
  const float* x        = (const float*)d_in[0];
  const float* gamma    = (const float*)d_in[1];
  const float* beta     = (const float*)d_in[2];
  const float* iscale   = (const float*)d_in[3];
  const float* qkv_b    = (const float*)d_in[4];
  const float* o_b      = (const float*)d_in[5];
  const float* gate_b   = (const float*)d_in[6];
  const float* up_b     = (const float*)d_in[7];
  const float* down_b   = (const float*)d_in[8];
  const float* a_qkv    = (const float*)d_in[9];
  const float* a_o      = (const float*)d_in[10];
  const float* a_gate   = (const float*)d_in[11];
  const float* a_up     = (const float*)d_in[12];
  const float* a_down   = (const float*)d_in[13];
  const float* n1w      = (const float*)d_in[14];
  const float* n2w      = (const float*)d_in[15];
  const int*   lidx     = (const int*)d_in[16];

  char* p = (char*)d_ws;
  auto alloc = [&](size_t bytes) { char* r = p; p += (bytes + 255) & ~(size_t)255; return r; };
  bf16*  Wqkv = (bf16*)alloc((size_t)3072*1024*2);
  bf16*  Wo   = (bf16*)alloc((size_t)1024*1024*2);
  bf16*  Wgu  = (bf16*)alloc((size_t)8192*1024*2);
  bf16*  Wd   = (bf16*)alloc((size_t)1024*4096*2);
  bf16*  hbuf = (bf16*)alloc((size_t)2048*1024*2);
  bf16*  qkvb = (bf16*)alloc((size_t)2048*3072*2);
  bf16*  attn = (bf16*)alloc((size_t)2048*1024*2);
  float* xat  = (float*)alloc((size_t)2048*1024*4);
  bf16*  h2   = (bf16*)alloc((size_t)2048*1024*2);
  bf16*  act  = (bf16*)alloc((size_t)2048*4096*2);
  float* out  = (float*)d_out;

  prep1<<<6144, 256, 0, stream>>>(qkv_b, a_qkv, o_b, a_o, x, n1w, gamma, beta, lidx,
                                  Wqkv, Wo, hbuf);
  gemm_bt<0,4><<<24*16, 256, 0, stream>>>(hbuf, Wqkv, 2048, 3072, 1024, 24,
                                          nullptr, qkvb, nullptr, nullptr, nullptr);
  attn_mega<<<1024, 256, 0, stream>>>(qkvb, attn, gate_b, up_b, down_b,
                                      a_gate, a_up, a_down, lidx, Wgu, Wd);
  gemm_bt<1,2><<<16*16, 256, 0, stream>>>(attn, Wo, 2048, 1024, 1024, 16,
                                          xat, nullptr, x, nullptr, nullptr);
  rmsnorm_k<<<2048, 256, 0, stream>>>(xat, n2w, gamma, beta, h2);
  gemm_bt<5,4><<<64*16, 256, 0, stream>>>(h2, Wgu, 2048, 8192, 1024, 64,
                                          nullptr, act, nullptr, nullptr, nullptr);
  gemm_bt<4,2><<<16*16, 256, 0, stream>>>(act, Wd, 2048, 1024, 4096, 16,
                                          out, nullptr, x, xat, iscale);
}